// Round 6
// baseline (739.373 us; speedup 1.0000x reference)
//
#include <hip/hip_runtime.h>
#include <hip/hip_fp16.h>

#define N_IN   100000
#define N_OUT  200000
#define C_IN   128
#define C_OUT  64
#define NK     27
#define MM     100000
#define BN_EPS 1e-5f

#define APAD   136   // Bls row stride in bf16 elems
#define TM     64    // rows per tile (one MFMA row-block per wave)
#define TPB    16    // tiles per block (software pipeline depth amortizer)

typedef short bf16x8 __attribute__((ext_vector_type(8)));
typedef float f32x4  __attribute__((ext_vector_type(4)));

__device__ __forceinline__ unsigned pack2_bf16(float a, float b) {
  unsigned ua = __float_as_uint(a);
  unsigned ub = __float_as_uint(b);
  ua = (ua + 0x7FFFu + ((ua >> 16) & 1u)) >> 16;          // low half
  ub = (ub + 0x7FFFu + ((ub >> 16) & 1u)) & 0xFFFF0000u;  // high half
  return ua | ub;
}

__device__ __forceinline__ unsigned pack2_f16(float lo, float hi) {
  __half2 h = __floats2half2_rn(lo, hi);
  return *(unsigned*)&h;
}

// fire-and-forget packed f16 atomic add; "memory" clobber also pins issue
// order: next-tile gathers stay ABOVE these, so they overlap the drain.
__device__ __forceinline__ void pk_atomic_f16(const void* addr, unsigned pw) {
  asm volatile("global_atomic_pk_add_f16 %0, %1, off"
               :: "v"((unsigned long long)addr), "v"(pw) : "memory");
}

// Combined converter:
//  blocks [0, 6250):  x f32 [N_IN][C_IN] -> xb bf16 (packed pairs)
//  blocks [6250, 6682): weight [k][ci][co] f32 -> wt [k][co][ci] bf16
__global__ void convert_kernel(const float* __restrict__ x, unsigned* __restrict__ xb,
                               const float* __restrict__ w, unsigned* __restrict__ wt) {
  if (blockIdx.x < 6250) {
    int id = blockIdx.x * 256 + threadIdx.x;          // [0, 1.6M)
    const float4* xs = (const float4*)x;
    float4 v0 = xs[2 * id];
    float4 v1 = xs[2 * id + 1];
    uint4 o;
    o.x = pack2_bf16(v0.x, v0.y);
    o.y = pack2_bf16(v0.z, v0.w);
    o.z = pack2_bf16(v1.x, v1.y);
    o.w = pack2_bf16(v1.z, v1.w);
    ((uint4*)xb)[id] = o;
  } else {
    int pidx = (blockIdx.x - 6250) * 256 + threadIdx.x;  // [0, 27*4096)
    int k   = pidx >> 12;
    int rem = pidx & 4095;
    int co  = rem >> 6;
    int ci0 = (rem & 63) * 2;
    const float* wk = w + (size_t)k * C_IN * C_OUT;
    float a = wk[ci0 * C_OUT + co];
    float b = wk[(ci0 + 1) * C_OUT + co];
    wt[pidx] = pack2_bf16(a, b);
  }
}

// v6: software-pipelined multi-tile scatter. Per tile j: issue maps(j+1),
// MFMA(j), issue gathers(j+1), issue atomics(j). Atomics(j) drain while
// tile j+1's loads are in flight — latency amortized across TPB tiles.
__global__ __launch_bounds__(256, 4) void scatter6_kernel(
    const uint4* __restrict__ xb,            // [N_IN][16] 16B-chunks (256 B/row)
    const unsigned short* __restrict__ wt,   // [k][co][ci] bf16
    const int* __restrict__ in_map,
    const int* __restrict__ out_map,
    unsigned short* __restrict__ acc16)
{
  __shared__ unsigned short Bls[C_OUT * APAD];

  const int t = threadIdx.x;
  const int k = blockIdx.y;

  // stage weight tile [co][ci] bf16, 16B chunks, coalesced
  {
    const uint4* src = (const uint4*)(wt + (size_t)k * C_OUT * C_IN);
    #pragma unroll
    for (int i = 0; i < 4; ++i) {
      int ch  = t + i * 256;        // 0..1023
      int co  = ch >> 4;
      int ci0 = (ch & 15) * 8;
      *(uint4*)&Bls[co * APAD + ci0] = src[ch];
    }
  }
  __syncthreads();

  const int wave = t >> 6;
  const int lane = t & 63;
  const int quad = lane >> 4;
  const int l15  = lane & 15;
  const int par  = l15 & 1;
  const int rb16 = wave * 16;           // this wave's 16 rows within the tile
  const size_t kb = (size_t)k * MM;
  const int tile0 = blockIdx.x * TPB;

  // ---- prologue: maps + gather for tile 0 (always live: mb <= 99328) ----
  int mb   = tile0 * TM;
  int arow = mb + rb16 + l15;
  int srcr = (arow < MM) ? in_map[kb + arow] : 0;
  int mrow = mb + rb16 + quad * 4;
  int4 o4;
  if (mrow + 3 < MM) {
    o4 = *(const int4*)(out_map + kb + mrow);
  } else {
    o4.x = (mrow + 0 < MM) ? out_map[kb + mrow + 0] : 0;
    o4.y = (mrow + 1 < MM) ? out_map[kb + mrow + 1] : 0;
    o4.z = (mrow + 2 < MM) ? out_map[kb + mrow + 2] : 0;
    o4.w = (mrow + 3 < MM) ? out_map[kb + mrow + 3] : 0;
  }
  uint4 a[4];
  {
    const uint4* xr = xb + (size_t)srcr * 16 + quad;
    a[0] = xr[0]; a[1] = xr[4]; a[2] = xr[8]; a[3] = xr[12];
  }

  for (int j = 0; j < TPB; ++j) {
    // ---- next-tile maps (uniform condition; issue under MFMA) ----
    int mb2 = (tile0 + j + 1) * TM;
    const bool more = (j + 1 < TPB) && (mb2 < MM);
    int nsrc = 0, nmrow = 0;
    int4 no4 = make_int4(0, 0, 0, 0);
    if (more) {
      int narow = mb2 + rb16 + l15;
      nsrc  = (narow < MM) ? in_map[kb + narow] : 0;
      nmrow = mb2 + rb16 + quad * 4;
      if (nmrow + 3 < MM) {
        no4 = *(const int4*)(out_map + kb + nmrow);
      } else {
        no4.x = (nmrow + 0 < MM) ? out_map[kb + nmrow + 0] : 0;
        no4.y = (nmrow + 1 < MM) ? out_map[kb + nmrow + 1] : 0;
        no4.z = (nmrow + 2 < MM) ? out_map[kb + nmrow + 2] : 0;
        no4.w = (nmrow + 3 < MM) ? out_map[kb + nmrow + 3] : 0;
      }
    }

    // ---- MFMA current tile ----
    f32x4 acc[4];
    #pragma unroll
    for (int ct = 0; ct < 4; ++ct) acc[ct] = (f32x4){0.f, 0.f, 0.f, 0.f};
    #pragma unroll
    for (int kk = 0; kk < 4; ++kk) {
      const int koff = kk * 32 + quad * 8;
      bf16x8 fa = *(const bf16x8*)&a[kk];
      bf16x8 b0 = *(const bf16x8*)&Bls[(l15) * APAD + koff];
      bf16x8 b1 = *(const bf16x8*)&Bls[(16 + l15) * APAD + koff];
      bf16x8 b2 = *(const bf16x8*)&Bls[(32 + l15) * APAD + koff];
      bf16x8 b3 = *(const bf16x8*)&Bls[(48 + l15) * APAD + koff];
      acc[0] = __builtin_amdgcn_mfma_f32_16x16x32_bf16(fa, b0, acc[0], 0, 0, 0);
      acc[1] = __builtin_amdgcn_mfma_f32_16x16x32_bf16(fa, b1, acc[1], 0, 0, 0);
      acc[2] = __builtin_amdgcn_mfma_f32_16x16x32_bf16(fa, b2, acc[2], 0, 0, 0);
      acc[3] = __builtin_amdgcn_mfma_f32_16x16x32_bf16(fa, b3, acc[3], 0, 0, 0);
    }

    // ---- next-tile gathers: issued BEFORE atomics so they fly during drain ----
    uint4 na[4];
    if (more) {
      const uint4* nxr = xb + (size_t)nsrc * 16 + quad;
      na[0] = nxr[0]; na[1] = nxr[4]; na[2] = nxr[8]; na[3] = nxr[12];
    }

    // ---- atomics for current tile (C/D: col = ct*16+l15, row = quad*4+i) ----
    int omv[4] = {o4.x, o4.y, o4.z, o4.w};
    #pragma unroll
    for (int ct = 0; ct < 4; ++ct) {
      f32x4 v = acc[ct];
      int colb = ct * 16 + (l15 & ~1);
      #pragma unroll
      for (int i = 0; i < 4; ++i) {
        float vn = __shfl_xor(v[i], 1);       // neighbor lane: col^1, same row
        float lo = par ? vn : v[i];
        float hi = par ? v[i] : vn;
        unsigned pw = pack2_f16(lo, hi);
        if (((i & 1) == par) && (mrow + i < MM)) {
          pk_atomic_f16(acc16 + (size_t)omv[i] * C_OUT + colb, pw);
        }
      }
    }

    if (!more) break;
    a[0] = na[0]; a[1] = na[1]; a[2] = na[2]; a[3] = na[3];
    o4 = no4; mrow = nmrow;
  }
}

// ---------- f16-accumulator reductions ----------
__global__ __launch_bounds__(256) void stats16_kernel(const unsigned* __restrict__ acc,
                                                      float* __restrict__ ws) {
  __shared__ float red[4][8][32];
  int t = threadIdx.x;
  int w = t & 31, sub = t >> 5;
  float s0 = 0, q0 = 0, s1 = 0, q1 = 0;
  for (int r = blockIdx.x * 8 + sub; r < N_OUT; r += gridDim.x * 8) {
    unsigned u = acc[(size_t)r * 32 + w];
    __half2 h = *(__half2*)&u;
    float a = __low2float(h), b = __high2float(h);
    s0 += a; q0 += a * a; s1 += b; q1 += b * b;
  }
  red[0][sub][w] = s0; red[1][sub][w] = q0;
  red[2][sub][w] = s1; red[3][sub][w] = q1;
  __syncthreads();
  if (t < 32) {
    float S0 = 0, Q0 = 0, S1 = 0, Q1 = 0;
    #pragma unroll
    for (int s = 0; s < 8; ++s) {
      S0 += red[0][s][t]; Q0 += red[1][s][t];
      S1 += red[2][s][t]; Q1 += red[3][s][t];
    }
    unsafeAtomicAdd(&ws[2 * t],      S0);
    unsafeAtomicAdd(&ws[64 + 2 * t], Q0);
    unsafeAtomicAdd(&ws[2 * t + 1],      S1);
    unsafeAtomicAdd(&ws[64 + 2 * t + 1], Q1);
  }
}

__global__ void prep_kernel(float* __restrict__ ws,
                            const float* __restrict__ gamma,
                            const float* __restrict__ beta) {
  int c = threadIdx.x;
  float mean = ws[c] * (1.0f / N_OUT);
  float var  = ws[64 + c] * (1.0f / N_OUT) - mean * mean;
  var = fmaxf(var, 0.0f);
  float sc = gamma[c] * rsqrtf(var + BN_EPS);
  ws[128 + c] = sc;
  ws[192 + c] = beta[c] - mean * sc;
}

__global__ void finalize16_kernel(const uint2* __restrict__ acc,
                                  float* __restrict__ out,
                                  const float* __restrict__ ws) {
  int i = blockIdx.x * 256 + threadIdx.x;  // float4 index, 3.2M exactly
  uint2 u = acc[i];
  __half2 h0 = *(__half2*)&u.x;
  __half2 h1 = *(__half2*)&u.y;
  int c0 = (i & 15) * 4;
  float s0 = ws[128 + c0], s1 = ws[129 + c0], s2 = ws[130 + c0], s3 = ws[131 + c0];
  float b0 = ws[192 + c0], b1 = ws[193 + c0], b2 = ws[194 + c0], b3 = ws[195 + c0];
  float4 v;
  v.x = fmaxf(fmaf(__low2float(h0),  s0, b0), 0.f);
  v.y = fmaxf(fmaf(__high2float(h0), s1, b1), 0.f);
  v.z = fmaxf(fmaf(__low2float(h1),  s2, b2), 0.f);
  v.w = fmaxf(fmaf(__high2float(h1), s3, b3), 0.f);
  ((float4*)out)[i] = v;
}

extern "C" void kernel_launch(void* const* d_in, const int* in_sizes, int n_in,
                              void* d_out, int out_size, void* d_ws, size_t ws_size,
                              hipStream_t stream) {
  const float* x      = (const float*)d_in[0];
  const float* weight = (const float*)d_in[1];
  const float* gamma  = (const float*)d_in[2];
  const float* beta   = (const float*)d_in[3];
  const int* in_map   = (const int*)d_in[4];
  const int* out_map  = (const int*)d_in[5];
  float* out   = (float*)d_out;
  float* stats = (float*)d_ws;

  // ws layout (total 53.6 MB — proven to fit by R5's fallback run)
  const size_t WT_OFF  = (size_t)1 << 20;
  const size_t XB_OFF  = (size_t)2 << 20;                 // 25.6 MB
  const size_t ACC_OFF = (size_t)28 << 20;                // 25.6 MB
  const size_t ACC_SZ  = (size_t)N_OUT * C_OUT * 2;

  unsigned* wt          = (unsigned*)((char*)d_ws + WT_OFF);
  unsigned* xb          = (unsigned*)((char*)d_ws + XB_OFF);
  unsigned short* acc16 = (unsigned short*)((char*)d_ws + ACC_OFF);

  hipMemsetAsync(d_ws, 0, 1024, stream);
  hipMemsetAsync(acc16, 0, ACC_SZ, stream);

  convert_kernel<<<6682, 256, 0, stream>>>(x, xb, weight, wt);

  // 98 blocks x: 98*TPB*TM = 100352 rows >= MM; y = 27 kernel offsets
  dim3 g((MM + TM * TPB - 1) / (TM * TPB), NK);
  scatter6_kernel<<<g, 256, 0, stream>>>((const uint4*)xb, (const unsigned short*)wt,
                                         in_map, out_map, acc16);

  stats16_kernel<<<1024, 256, 0, stream>>>((const unsigned*)acc16, stats);
  prep_kernel<<<1, 64, 0, stream>>>(stats, gamma, beta);
  finalize16_kernel<<<(N_OUT * C_OUT / 4) / 256, 256, 0, stream>>>(
      (const uint2*)acc16, out, stats);
}